// Round 7
// baseline (452.190 us; speedup 1.0000x reference)
//
#include <hip/hip_runtime.h>

// DecoderCell v7: 6 GEMMs on an 8-phase-style counted-vmcnt pipeline.
// BM=256 x BN=128 x BK=64, 8 waves, 3 LDS buffers (144KB), 2-deep prefetch,
// vmcnt(6) per K-tile (T3+T4), setprio around MFMA clusters (T5), v6's
// both-sides XOR swizzle (T2, measured 0 conflicts). rsample fused into co.
//
// h_0 layout: [gen 0:512 | con 512:768 | mean 768:832 | std 832:896 | gi 896:960 | factor 960:1088]
// A_con[32768][640] = [input 256 | factor 128 | h_con->hnew_con 256]  (swizzled)
// A_gen[32768][576] = [gi 64 | h_gen->hnew_gen 512]                   (swizzled)

typedef short  s16x8 __attribute__((ext_vector_type(8)));
typedef float  f32x4 __attribute__((ext_vector_type(4)));
typedef unsigned short ush;

#define OUTP 1088
#define NROW 32768
#define BUFSZ 24576   // (256*64 A + 128*64 B) ush per buffer

__device__ __forceinline__ int swz(int k, int row) {
  return (k & ~63) | ((k & 63) ^ ((row & 7) << 3));
}
__device__ __forceinline__ ush f2bf(float f) {
  union { float f; unsigned int u; } v; v.f = f;
  unsigned int u = v.u;
  return (ush)((u + 0x7FFFu + ((u >> 16) & 1u)) >> 16);  // RNE
}
__device__ __forceinline__ float bf2f(ush b) {
  union { unsigned int u; float f; } v; v.u = ((unsigned int)b) << 16;
  return v.f;
}
__device__ __forceinline__ float sigm(float x) { return 1.f / (1.f + __expf(-x)); }
__device__ __forceinline__ float tanh_(float x) { return 2.f / (1.f + __expf(-2.f * x)) - 1.f; }

__device__ __forceinline__ f32x4 mfma16(s16x8 a, s16x8 b, f32x4 c) {
  return __builtin_amdgcn_mfma_f32_16x16x32_bf16(a, b, c, 0, 0, 0);
}
__device__ __forceinline__ s16x8 ldb8(const ush* p) {
  return *reinterpret_cast<const s16x8*>(p);
}
__device__ __forceinline__ void gld16(const ush* g, ush* l) {
  __builtin_amdgcn_global_load_lds(
      (const __attribute__((address_space(1))) unsigned int*)g,
      (__attribute__((address_space(3))) unsigned int*)l, 16, 0, 0);
}
__device__ __forceinline__ ushort4 pack4(float4 a) {
  ushort4 o; o.x = f2bf(a.x); o.y = f2bf(a.y); o.z = f2bf(a.z); o.w = f2bf(a.w);
  return o;
}

// ---- prep: A_con = [input|factor|h_con] + A_gen h-section, bf16 swizzled ---
__global__ void prepA_kernel(const float* __restrict__ in, const float* __restrict__ h0,
                             ush* __restrict__ Acon, ush* __restrict__ Agen) {
  int t = blockIdx.x * 256 + threadIdx.x;      // 32768 * 144
  int row = t / 144, c = t % 144;
  if (c < 80) {
    int c8 = c * 8;
    const float* src;
    if (c8 < 256)      src = &in[(size_t)row * 256 + c8];
    else if (c8 < 384) src = &h0[(size_t)row * OUTP + 960 + (c8 - 256)];
    else               src = &h0[(size_t)row * OUTP + 512 + (c8 - 384)];
    float4 a = *reinterpret_cast<const float4*>(src);
    float4 b = *reinterpret_cast<const float4*>(src + 4);
    ushort4* d = reinterpret_cast<ushort4*>(&Acon[(size_t)row * 640 + swz(c8, row)]);
    d[0] = pack4(a); d[1] = pack4(b);
  } else {
    int c8 = (c - 80) * 8;
    float4 a = *reinterpret_cast<const float4*>(&h0[(size_t)row * OUTP + c8]);
    float4 b = *reinterpret_cast<const float4*>(&h0[(size_t)row * OUTP + c8 + 4]);
    ushort4* d = reinterpret_cast<ushort4*>(&Agen[(size_t)row * 576 + swz(64 + c8, row)]);
    d[0] = pack4(a); d[1] = pack4(b);
  }
}

// ---- prep: con weights -> [Wih(384)|Whh(256)], swizzled --------------------
__global__ void packBcon_kernel(const float* __restrict__ wih, const float* __restrict__ whh,
                                ush* __restrict__ B1, ush* __restrict__ B2) {
  int r = blockIdx.x;          // 0..767
  int c4 = threadIdx.x * 4;    // 0..636
  float4 v = (c4 < 384) ? *reinterpret_cast<const float4*>(&wih[(size_t)r * 384 + c4])
                        : *reinterpret_cast<const float4*>(&whh[(size_t)r * 256 + (c4 - 384)]);
  int pc = swz(c4, r);
  ush* dst = (r < 512) ? &B1[(size_t)r * 640 + pc] : &B2[(size_t)(r - 512) * 640 + pc];
  *reinterpret_cast<ushort4*>(dst) = pack4(v);
}

// ---- prep: gen weights -> [Wih(64)|Whh(512)], swizzled ---------------------
__global__ void packBgen_kernel(const float* __restrict__ wih, const float* __restrict__ whh,
                                ush* __restrict__ B1, ush* __restrict__ B2) {
  int r = blockIdx.x;          // 0..1535
  int c4 = threadIdx.x * 4;    // 0..572
  float4 v = (c4 < 64) ? *reinterpret_cast<const float4*>(&wih[(size_t)r * 64 + c4])
                       : *reinterpret_cast<const float4*>(&whh[(size_t)r * 512 + (c4 - 64)]);
  int pc = swz(c4, r);
  ush* dst = (r < 1024) ? &B1[(size_t)r * 576 + pc] : &B2[(size_t)(r - 1024) * 576 + pc];
  *reinterpret_cast<ushort4*>(dst) = pack4(v);
}

// ---- prep: co_W f32->bf16, swizzled (128x256) ------------------------------
__global__ void cvtco_kernel(const float* __restrict__ src, ush* __restrict__ dst) {
  int i = blockIdx.x * 256 + threadIdx.x;      // 128*64
  int row = i >> 6, c4 = (i & 63) * 4;
  float4 v = *reinterpret_cast<const float4*>(&src[(size_t)row * 256 + c4]);
  *reinterpret_cast<ushort4*>(&dst[(size_t)row * 256 + swz(c4, row)]) = pack4(v);
}

// ---- prep: row-L2-normalize fac_W (128x512) -> bf16, swizzled --------------
__global__ void facnorm_kernel(const float* __restrict__ w, ush* __restrict__ dst) {
  int row = blockIdx.x;       // 128
  int lane = threadIdx.x;     // 64
  float v[8]; float s = 0.f;
  #pragma unroll
  for (int i = 0; i < 8; ++i) { v[i] = w[row * 512 + lane * 8 + i]; s += v[i] * v[i]; }
  #pragma unroll
  for (int off = 32; off; off >>= 1) s += __shfl_xor(s, off);
  float scale = 1.f / fmaxf(sqrtf(s), 1e-12f);
  int pc = swz(lane * 8, row);
  #pragma unroll
  for (int i = 0; i < 8; ++i) dst[row * 512 + pc + i] = f2bf(v[i] * scale);
}

// ---- GEMM: 256x128 tile, BK=64, 3-buffer counted-vmcnt pipeline ------------
// EPI: 0 = zr-gate (z->st1 linear, rh->st2 swz), 1 = n-gate (h_new -> out f32
//      coalesced + st1 swz), 2 = co + rsample (mean/std/gi -> out, gi->giout),
//      3 = factor (f32 -> out, coalesced)
template<int EPI, int KTOT, int KA1, int SA1, int SA2, int SB,
         int NT, int NHALF, int SAH, int OOFS, int SHN>
__global__ __launch_bounds__(512, 2) void gemm8_kernel(
    const ush* __restrict__ A1, const ush* __restrict__ A2,
    const ush* __restrict__ B,
    const float* __restrict__ bih, const float* __restrict__ bhh,
    const ush* __restrict__ Ah,
    const ush* __restrict__ zbuf,
    ush* __restrict__ st1, ush* __restrict__ st2,
    const float* __restrict__ eps, ush* __restrict__ giout,
    float* __restrict__ out)
{
  __shared__ __align__(16) ush S[3 * BUFSZ];   // 144 KB
  const int nwg = gridDim.x;
  const int wg = (blockIdx.x & 7) * (nwg >> 3) + (blockIdx.x >> 3);  // XCD-chunked
  const int mt = wg / NT, nt = wg % NT;
  const int m0 = mt * 256, n0 = nt * 128;
  const int tid = threadIdx.x;
  const int wv = tid >> 6, lane = tid & 63;
  const int ln = lane & 15, lk = lane >> 4;
  const int wm = wv >> 1, wn = wv & 1;
  const int srow = lane >> 3;          // 0..7
  const int scol = (lane & 7) * 8;
  const int xs = (ln & 7) << 3;
  const int NK = KTOT / 64;

  f32x4 acc[4][4] = {};

  // ---- prologue: stage tiles 0,1 into buffers 0,1
  #pragma unroll
  for (int tt = 0; tt < 2; ++tt) {
    const int k2 = tt * 64;
    const ush* Ab; int sa, kk;
    if (KA1 >= KTOT || k2 < KA1) { Ab = A1; sa = SA1; kk = k2; }
    else                         { Ab = A2; sa = SA2; kk = k2 - KA1; }
    ush* Sd = &S[tt * BUFSZ];
    #pragma unroll
    for (int l = 0; l < 4; ++l)
      gld16(Ab + (size_t)(m0 + l * 64 + wv * 8 + srow) * sa + kk + scol,
            Sd + (l * 64 + wv * 8) * 64);
    #pragma unroll
    for (int l = 0; l < 2; ++l)
      gld16(B + (size_t)(n0 + l * 64 + wv * 8 + srow) * SB + k2 + scol,
            Sd + 16384 + (l * 64 + wv * 8) * 64);
  }

  // ---- main loop: per K-tile, vmcnt(6) publish + 4 phases
  int cur = 0;
  for (int t = 0; t < NK; ++t) {
    if (t < NK - 1) { asm volatile("s_waitcnt vmcnt(6)" ::: "memory"); }
    else            { asm volatile("s_waitcnt vmcnt(0)" ::: "memory"); }
    __builtin_amdgcn_s_barrier();
    __builtin_amdgcn_sched_barrier(0);
    const ush* As = &S[cur * BUFSZ];
    const ush* Bs = As + 16384;
    const int nxt = (cur >= 1) ? cur - 1 : 2;      // (t+2)%3
    ush* Sd = &S[nxt * BUFSZ];
    const bool doStage = (t + 2 < NK);
    const int k2 = (t + 2) * 64;
    const ush* Ab; int sa, kk;
    if (KA1 >= KTOT || k2 < KA1) { Ab = A1; sa = SA1; kk = k2; }
    else                         { Ab = A2; sa = SA2; kk = k2 - KA1; }

    s16x8 bf0, bf1, bf2, bf3;
    #pragma unroll
    for (int p = 0; p < 4; ++p) {
      const int kk2 = p >> 1, ih = p & 1;
      const int kb = (kk2 * 32 + lk * 8) ^ xs;
      if (ih == 0) {
        bf0 = ldb8(&Bs[(wn * 64 +  0 + ln) * 64 + kb]);
        bf1 = ldb8(&Bs[(wn * 64 + 16 + ln) * 64 + kb]);
        bf2 = ldb8(&Bs[(wn * 64 + 32 + ln) * 64 + kb]);
        bf3 = ldb8(&Bs[(wn * 64 + 48 + ln) * 64 + kb]);
      }
      s16x8 af0 = ldb8(&As[(wm * 64 + (ih * 2 + 0) * 16 + ln) * 64 + kb]);
      s16x8 af1 = ldb8(&As[(wm * 64 + (ih * 2 + 1) * 16 + ln) * 64 + kb]);
      if (doStage) {
        if (p == 0) {
          gld16(Ab + (size_t)(m0 +   0 + wv * 8 + srow) * sa + kk + scol, Sd + (  0 + wv * 8) * 64);
          gld16(Ab + (size_t)(m0 +  64 + wv * 8 + srow) * sa + kk + scol, Sd + ( 64 + wv * 8) * 64);
        } else if (p == 1) {
          gld16(Ab + (size_t)(m0 + 128 + wv * 8 + srow) * sa + kk + scol, Sd + (128 + wv * 8) * 64);
          gld16(Ab + (size_t)(m0 + 192 + wv * 8 + srow) * sa + kk + scol, Sd + (192 + wv * 8) * 64);
        } else if (p == 2) {
          gld16(B + (size_t)(n0 +  0 + wv * 8 + srow) * SB + k2 + scol, Sd + 16384 + ( 0 + wv * 8) * 64);
          gld16(B + (size_t)(n0 + 64 + wv * 8 + srow) * SB + k2 + scol, Sd + 16384 + (64 + wv * 8) * 64);
        }
      }
      __builtin_amdgcn_s_barrier();
      __builtin_amdgcn_s_setprio(1);
      const int i0 = ih * 2, i1 = ih * 2 + 1;
      acc[i0][0] = mfma16(af0, bf0, acc[i0][0]);
      acc[i0][1] = mfma16(af0, bf1, acc[i0][1]);
      acc[i0][2] = mfma16(af0, bf2, acc[i0][2]);
      acc[i0][3] = mfma16(af0, bf3, acc[i0][3]);
      acc[i1][0] = mfma16(af1, bf0, acc[i1][0]);
      acc[i1][1] = mfma16(af1, bf1, acc[i1][1]);
      acc[i1][2] = mfma16(af1, bf2, acc[i1][2]);
      acc[i1][3] = mfma16(af1, bf3, acc[i1][3]);
      __builtin_amdgcn_s_setprio(0);
      __builtin_amdgcn_s_barrier();
    }
    cur = (cur == 2) ? 0 : cur + 1;
  }

  // ---- epilogues (overlay S) -------------------------------------------------
  ush* Ls = S;                              // 256 x 128 bf16 (64 KB)
  float* Lf = reinterpret_cast<float*>(S);  // 256 x 132 f32 (135 KB)

  if constexpr (EPI == 0) {          // z | r gates
    const bool isz = (n0 < NHALF);
    #pragma unroll
    for (int i = 0; i < 4; ++i) {
      #pragma unroll
      for (int j = 0; j < 4; ++j) {
        const int jl = wn * 64 + j * 16 + ln;
        const int jg = n0 + jl;
        const float bb = bih[jg] + bhh[jg];
        #pragma unroll
        for (int r = 0; r < 4; ++r) {
          const int rl = wm * 64 + i * 16 + lk * 4 + r;
          float sv = sigm(acc[i][j][r] + bb);
          if (!isz) sv *= bf2f(Ah[(size_t)(m0 + rl) * SAH + swz(jg - NHALF, rl)]);
          Ls[rl * 128 + (jl ^ ((rl & 7) << 3))] = f2bf(sv);
        }
      }
    }
    __syncthreads();
    #pragma unroll
    for (int q = 0; q < 8; ++q) {
      int idx = q * 512 + tid;
      int r = idx >> 4, c8 = (idx & 15) * 8;
      float4 v = *reinterpret_cast<const float4*>(&Ls[r * 128 + (c8 ^ ((r & 7) << 3))]);
      if (isz) *reinterpret_cast<float4*>(&st1[(size_t)(m0 + r) * NHALF + n0 + c8]) = v;
      else     *reinterpret_cast<float4*>(&st2[(size_t)(m0 + r) * NHALF +
                                               swz(n0 - NHALF + c8, r)]) = v;
    }
  } else if constexpr (EPI == 1) {   // n gate + combine; h_new -> st1(bf16) + out(f32)
    #pragma unroll
    for (int i = 0; i < 4; ++i) {
      #pragma unroll
      for (int j = 0; j < 4; ++j) {
        const int jl = wn * 64 + j * 16 + ln;
        const int jg = n0 + jl;
        const float bb = bih[2 * NHALF + jg] + bhh[2 * NHALF + jg];
        #pragma unroll
        for (int r = 0; r < 4; ++r) {
          const int rl = wm * 64 + i * 16 + lk * 4 + r;
          const size_t m = (size_t)(m0 + rl);
          float n = tanh_(acc[i][j][r] + bb);
          float z = bf2f(zbuf[m * NHALF + jg]);
          float h = bf2f(Ah[m * SAH + swz(jg, rl)]);
          float hv = fminf(fmaxf(z * h + (1.f - z) * n, -5.f), 5.f);
          Ls[rl * 128 + (jl ^ ((rl & 7) << 3))] = f2bf(hv);
        }
      }
    }
    __syncthreads();
    #pragma unroll
    for (int q = 0; q < 8; ++q) {
      int idx = q * 512 + tid;
      int r = idx >> 4, c8 = (idx & 15) * 8;
      union { float4 f; ush u[8]; } U;
      U.f = *reinterpret_cast<const float4*>(&Ls[r * 128 + (c8 ^ ((r & 7) << 3))]);
      *reinterpret_cast<float4*>(&st1[(size_t)(m0 + r) * SHN + swz(n0 + c8, r)]) = U.f;
      float4 o0 = { bf2f(U.u[0]), bf2f(U.u[1]), bf2f(U.u[2]), bf2f(U.u[3]) };
      float4 o1 = { bf2f(U.u[4]), bf2f(U.u[5]), bf2f(U.u[6]), bf2f(U.u[7]) };
      float* ob = &out[(size_t)(m0 + r) * OUTP + OOFS + n0 + c8];
      *reinterpret_cast<float4*>(ob) = o0;
      *reinterpret_cast<float4*>(ob + 4) = o1;
    }
  } else if constexpr (EPI == 2) {   // co + rsample
    #pragma unroll
    for (int i = 0; i < 4; ++i) {
      #pragma unroll
      for (int j = 0; j < 4; ++j) {
        const int jl = wn * 64 + j * 16 + ln;
        const float bb = bih[jl];
        #pragma unroll
        for (int r = 0; r < 4; ++r) {
          const int rl = wm * 64 + i * 16 + lk * 4 + r;
          float v = acc[i][j][r] + bb;
          Lf[rl * 132 + jl] = (jl < 64) ? v : __expf(0.5f * v);
        }
      }
    }
    __syncthreads();
    #pragma unroll
    for (int q = 0; q < 32; ++q) {
      int idx = q * 512 + tid;
      int r = idx >> 6, j = idx & 63;
      float mean = Lf[r * 132 + j];
      float sd   = Lf[r * 132 + 64 + j];
      float g = mean + sd * eps[(size_t)(m0 + r) * 64 + j];
      size_t mo = (size_t)(m0 + r) * OUTP;
      out[mo + 768 + j] = mean;
      out[mo + 832 + j] = sd;
      out[mo + 896 + j] = g;
      giout[(size_t)(m0 + r) * 576 + (j ^ ((r & 7) << 3))] = f2bf(g);
    }
  } else {                           // factor -> out f32, coalesced via LDS
    #pragma unroll
    for (int i = 0; i < 4; ++i) {
      #pragma unroll
      for (int j = 0; j < 4; ++j) {
        const int jl = wn * 64 + j * 16 + ln;
        #pragma unroll
        for (int r = 0; r < 4; ++r) {
          const int rl = wm * 64 + i * 16 + lk * 4 + r;
          Lf[rl * 132 + jl] = acc[i][j][r];
        }
      }
    }
    __syncthreads();
    #pragma unroll
    for (int q = 0; q < 16; ++q) {
      int idx = q * 512 + tid;
      int r = idx >> 5, c4 = (idx & 31) * 4;
      *reinterpret_cast<float4*>(&out[(size_t)(m0 + r) * OUTP + 960 + c4]) =
          *reinterpret_cast<const float4*>(&Lf[r * 132 + c4]);
    }
  }
}

extern "C" void kernel_launch(void* const* d_in, const int* in_sizes, int n_in,
                              void* d_out, int out_size, void* d_ws, size_t ws_size,
                              hipStream_t stream) {
  const float* input   = (const float*)d_in[0];
  const float* h0      = (const float*)d_in[1];
  const float* eps     = (const float*)d_in[2];
  const float* gen_Wih = (const float*)d_in[3];
  const float* gen_bih = (const float*)d_in[4];
  const float* gen_Whh = (const float*)d_in[5];
  const float* gen_bhh = (const float*)d_in[6];
  const float* con_Wih = (const float*)d_in[7];
  const float* con_bih = (const float*)d_in[8];
  const float* con_Whh = (const float*)d_in[9];
  const float* con_bhh = (const float*)d_in[10];
  const float* fac_W   = (const float*)d_in[11];
  const float* co_W    = (const float*)d_in[12];
  const float* co_b    = (const float*)d_in[13];
  float* out = (float*)d_out;

  ush* ws = (ush*)d_ws;
  ush* A_gen  = ws;                                  // 32768*576
  ush* A_con  = A_gen + (size_t)NROW * 576;          // 32768*640
  ush* z_con  = A_con + (size_t)NROW * 640;          // 32768*256
  ush* rh_con = z_con + (size_t)NROW * 256;          // 32768*256
  ush* B1c    = rh_con + (size_t)NROW * 256;         // 512*640
  ush* B2c    = B1c + 512 * 640;                     // 256*640
  ush* B1g    = B2c + 256 * 640;                     // 1024*576
  ush* B2g    = B1g + 1024 * 576;                    // 512*576
  ush* coWb   = B2g + 512 * 576;                     // 128*256
  ush* facWn  = coWb + 128 * 256;                    // 128*512
  // aliases over dead con-phase buffers (gen phase runs after co):
  ush* z_gen  = A_con;                               // 32768*512 <= A_con
  ush* rh_gen = z_con;                               // 32768*512 == z_con+rh_con

  // ---- prep ----
  packBcon_kernel<<<768, 160, 0, stream>>>(con_Wih, con_Whh, B1c, B2c);
  packBgen_kernel<<<1536, 144, 0, stream>>>(gen_Wih, gen_Whh, B1g, B2g);
  cvtco_kernel<<<32, 256, 0, stream>>>(co_W, coWb);
  facnorm_kernel<<<128, 64, 0, stream>>>(fac_W, facWn);
  prepA_kernel<<<18432, 256, 0, stream>>>(input, h0, A_con, A_gen);

  // ---- controller: z,r -> rh ; n -> h_new ; co + rsample ----
  gemm8_kernel<0, 640, 640, 640, 640, 640, 4, 256, 640, 0, 0>
      <<<512, 512, 0, stream>>>(A_con, A_con, B1c, con_bih, con_bhh,
                                A_con + 384, nullptr, z_con, rh_con,
                                nullptr, nullptr, out);
  gemm8_kernel<1, 640, 384, 640, 256, 640, 2, 256, 640, 512, 640>
      <<<256, 512, 0, stream>>>(A_con, rh_con, B2c, con_bih, con_bhh,
                                A_con + 384, z_con, A_con + 384, nullptr,
                                nullptr, nullptr, out);
  gemm8_kernel<2, 256, 256, 640, 640, 256, 1, 64, 640, 0, 0>
      <<<128, 512, 0, stream>>>(A_con + 384, A_con + 384, coWb, co_b, co_b,
                                nullptr, nullptr, nullptr, nullptr,
                                eps, A_gen, out);

  // ---- generator: z,r -> rh ; n -> h_new ; factor ----
  gemm8_kernel<0, 576, 576, 576, 576, 576, 8, 512, 576, 0, 0>
      <<<1024, 512, 0, stream>>>(A_gen, A_gen, B1g, gen_bih, gen_bhh,
                                 A_gen + 64, nullptr, z_gen, rh_gen,
                                 nullptr, nullptr, out);
  gemm8_kernel<1, 576, 64, 576, 512, 576, 4, 512, 576, 0, 576>
      <<<512, 512, 0, stream>>>(A_gen, rh_gen, B2g, gen_bih, gen_bhh,
                                A_gen + 64, z_gen, A_gen + 64, nullptr,
                                nullptr, nullptr, out);
  gemm8_kernel<3, 512, 512, 576, 576, 512, 1, 0, 576, 960, 0>
      <<<128, 512, 0, stream>>>(A_gen + 64, A_gen + 64, facWn, gen_bih, gen_bhh,
                                nullptr, nullptr, nullptr, nullptr,
                                nullptr, nullptr, out);
}